// Round 1
// 254.845 us; speedup vs baseline: 1.0965x; 1.0965x over previous
//
#include <hip/hip_runtime.h>
#include <hip/hip_bf16.h>

#define NH 16
#define HD 64
#define EMB 1024
#define BB 4
#define TT 2048
#define MTOT (BB*TT)        // 8192 rows
#define N1 (3*NH*HD)        // 3072
#define KD EMB              // 1024

#define BM 128
#define BN 128
#define BK 32

// q scale: (1/sqrt(HD)) * log2(e) — softmax computed in exp2 domain
#define QSCALE 0.18033688011112042f
// fixed softmax "max" in exp2 domain: scores ~N(0,1.44^2), max over 1.3e8 ~ 9.
// Any fixed value works mathematically (final 1/l normalization cancels it);
// 14 keeps P well inside bf16 normal range both directions.
#define FMAX 14.0f

typedef __bf16 bf16x8 __attribute__((ext_vector_type(8)));
typedef __bf16 bf16x4 __attribute__((ext_vector_type(4)));
typedef float  f32x4  __attribute__((ext_vector_type(4)));
typedef __hip_bfloat16 hbf;

__device__ __forceinline__ void async_copy16(const hbf* g, hbf* l) {
    __builtin_amdgcn_global_load_lds(
        (const __attribute__((address_space(1))) void*)g,
        (__attribute__((address_space(3))) void*)l, 16, 0, 0);
}

__device__ __forceinline__ bf16x4 pack4(float x0, float x1, float x2, float x3) {
    union { bf16x4 v; hbf a[4]; } u;
    u.a[0] = __float2bfloat16(x0);
    u.a[1] = __float2bfloat16(x1);
    u.a[2] = __float2bfloat16(x2);
    u.a[3] = __float2bfloat16(x3);
    return u.v;
}

// ---------------- conversion kernels ----------------

__global__ __launch_bounds__(256) void f32_to_bf16_v4(const float* __restrict__ in,
                                                      hbf* __restrict__ out, int n4) {
    int i = blockIdx.x * blockDim.x + threadIdx.x;
    if (i < n4) {
        float4 v = ((const float4*)in)[i];
        *(bf16x4*)(out + 4 * (size_t)i) = pack4(v.x, v.y, v.z, v.w);
    }
}

// LDS-tiled transposing convert: out[c*R + r] = bf16(in[r*C + c]); R,C % 64 == 0
__global__ __launch_bounds__(256) void f32_to_bf16_T(const float* __restrict__ in,
                                                     hbf* __restrict__ out, int R, int C) {
    __shared__ float T[64][65];
    int bc = blockIdx.x % (C / 64), br = blockIdx.x / (C / 64);
    int r0 = br * 64, c0 = bc * 64;
    int tr = threadIdx.x >> 6, tc = threadIdx.x & 63;
    #pragma unroll
    for (int i = 0; i < 16; ++i)
        T[4 * i + tr][tc] = in[(size_t)(r0 + 4 * i + tr) * C + c0 + tc];
    __syncthreads();
    #pragma unroll
    for (int i = 0; i < 16; ++i)
        out[(size_t)(c0 + 4 * i + tr) * R + r0 + tc] = __float2bfloat16(T[tc][4 * i + tr]);
}

// ---------------- tiled GEMM core (m97 structure) ----------------

#define GEMM_STAGE(Sdst, Gsrc, ld)                                            \
    {                                                                         \
        _Pragma("unroll")                                                     \
        for (int q = 0; q < 2; ++q) {                                         \
            int e = q * 2048 + tid * 8;                                       \
            int row = e >> 5, col = e & 31;                                   \
            async_copy16(Gsrc + (size_t)row * (ld) + col,                     \
                         Sdst + q * 2048 + (tid & ~63) * 8);                  \
        }                                                                     \
    }

__global__ __launch_bounds__(256) void gemm_qkv(
    const hbf* __restrict__ A, const hbf* __restrict__ Bt,
    hbf* __restrict__ qh, hbf* __restrict__ kh, hbf* __restrict__ vt)
{
    __shared__ __align__(16) hbf As[BM * BK];
    __shared__ __align__(16) hbf Bs[BN * BK];
    int tid = threadIdx.x;
    int wv = tid >> 6, lane = tid & 63;
    int g = lane >> 4, c = lane & 15;
    int wr = wv >> 1, wc = wv & 1;
    int bn = blockIdx.x % (N1 / BN);
    int bm = blockIdx.x / (N1 / BN);
    int m0 = bm * BM, n0 = bn * BN;

    f32x4 acc[4][4];
    #pragma unroll
    for (int i = 0; i < 4; ++i)
        #pragma unroll
        for (int j = 0; j < 4; ++j) acc[i][j] = (f32x4){0.f, 0.f, 0.f, 0.f};

    for (int k0 = 0; k0 < KD; k0 += BK) {
        const hbf* Ag = A  + (size_t)m0 * KD + k0;
        const hbf* Bg = Bt + (size_t)n0 * KD + k0;
        GEMM_STAGE(As, Ag, KD);
        GEMM_STAGE(Bs, Bg, KD);
        __syncthreads();
        bf16x8 af[4], bf[4];
        #pragma unroll
        for (int mi = 0; mi < 4; ++mi)
            af[mi] = *(const bf16x8*)(As + (wr * 64 + mi * 16 + c) * BK + g * 8);
        #pragma unroll
        for (int ni = 0; ni < 4; ++ni)
            bf[ni] = *(const bf16x8*)(Bs + (wc * 64 + ni * 16 + c) * BK + g * 8);
        #pragma unroll
        for (int mi = 0; mi < 4; ++mi)
            #pragma unroll
            for (int ni = 0; ni < 4; ++ni)
                acc[mi][ni] = __builtin_amdgcn_mfma_f32_16x16x32_bf16(af[mi], bf[ni], acc[mi][ni], 0, 0, 0);
        __syncthreads();
    }

    int colbase = n0 + wc * 64;
    int which = colbase / (NH * HD);
    int h = (colbase % (NH * HD)) / HD;
    int b = m0 / TT;
    float scale = (which == 0) ? QSCALE : 1.0f;
    if (which < 2) {
        hbf* dst = (which == 0) ? qh : kh;
        dst += ((size_t)b * NH + h) * TT * HD;
        #pragma unroll
        for (int mi = 0; mi < 4; ++mi)
            #pragma unroll
            for (int ni = 0; ni < 4; ++ni) {
                int d = ni * 16 + c;
                #pragma unroll
                for (int r = 0; r < 4; ++r) {
                    int t = (m0 + wr * 64 + mi * 16 + g * 4 + r) % TT;
                    dst[(size_t)t * HD + d] = __float2bfloat16(acc[mi][ni][r] * scale);
                }
            }
    } else {
        hbf* dst = vt + ((size_t)b * NH + h) * TT * HD;   // [HD][TT] per head
        #pragma unroll
        for (int mi = 0; mi < 4; ++mi)
            #pragma unroll
            for (int ni = 0; ni < 4; ++ni) {
                int d = ni * 16 + c;
                #pragma unroll
                for (int r = 0; r < 4; ++r) {
                    int t = (m0 + wr * 64 + mi * 16 + g * 4 + r) % TT;
                    dst[(size_t)d * TT + t] = __float2bfloat16(acc[mi][ni][r]);
                }
            }
    }
}

// ---------------- flash attention v5: fixed-max softmax, l via MFMA ----------------
// Block = 512 thr = 8 waves, 128-q supertile (wave wv owns q rows qb+16wv..+15).
// Stage K[128x64] + V^T[64x128] per step (global_load_lds, XOR-swizzled source).
// S^T = K·Q^T with C seeded to -FMAX (softmax in exp2 domain with FIXED max:
// mathematically exact after 1/l normalization; no running max, no rescale).
// l computed on the matrix pipe: every row of mfma(ones, P^T) is the col-sum.
// Causal balance: block runs supertile pair (pi, 15-pi) → uniform 17 stages.

__global__ __launch_bounds__(512, 4) void attn(
    const hbf* __restrict__ qh, const hbf* __restrict__ kh, const hbf* __restrict__ vt,
    hbf* __restrict__ y)
{
    __shared__ __align__(16) hbf Ks[128 * 64];     // 16 KB [key][dim-swz]
    __shared__ __align__(16) hbf Vs[64 * 128];     // 16 KB [dim][key-swz]
    __shared__ __align__(16) hbf Ps[8][16 * 64];   // 16 KB per-wave P^T

    int tid = threadIdx.x;
    int wv = tid >> 6, lane = tid & 63;
    int g = lane >> 4, c = lane & 15;
    int c7 = c & 7;

    int bh = blockIdx.x >> 3;
    int pi = blockIdx.x & 7;
    int b = bh >> 4, h = bh & 15;

    const hbf* Q = qh + (size_t)bh * TT * HD;
    const hbf* K = kh + (size_t)bh * TT * HD;
    const hbf* V = vt + (size_t)bh * TT * HD;   // [HD][TT]
    hbf* Pq = &Ps[wv][0];

    // all-ones A-fragment for the l column-sum MFMA
    union { bf16x8 v; hbf a[8]; } uo;
    #pragma unroll
    for (int i = 0; i < 8; ++i) uo.a[i] = __float2bfloat16(1.0f);
    const bf16x8 ones8 = uo.v;

    #pragma unroll
    for (int pass = 0; pass < 2; ++pass) {
        int sst = pass ? (15 - pi) : pi;
        int qb = sst * 128;
        int q0 = qb + wv * 16;
        int kend = q0 + 16;
        int kmax = qb + 128;

        bf16x8 aq0 = *(const bf16x8*)(Q + (size_t)(q0 + c) * HD + g * 8);
        bf16x8 aq1 = *(const bf16x8*)(Q + (size_t)(q0 + c) * HD + 32 + g * 8);

        f32x4 lacc = (f32x4){0.f, 0.f, 0.f, 0.f};
        f32x4 o[4];
        #pragma unroll
        for (int d = 0; d < 4; ++d) o[d] = (f32x4){0.f, 0.f, 0.f, 0.f};

        for (int k0 = 0; k0 < kmax; k0 += 128) {
            __syncthreads();   // prior stage's LDS reads complete
            // stage K tile 128x64: LDS[key][sblk] = K[k0+key][(sblk^(key&7))*8..]
            #pragma unroll
            for (int it = 0; it < 2; ++it) {
                int e = it * 4096 + tid * 8;
                int key = e >> 6, sblk = (e >> 3) & 7;
                int dblk = sblk ^ (key & 7);
                async_copy16(K + (size_t)(k0 + key) * HD + dblk * 8,
                             Ks + it * 4096 + (tid & ~63) * 8);
            }
            // stage V tile 64x128: LDS[dim][kb] = V[dim][k0 + (kb^(dim&7))*8..]
            #pragma unroll
            for (int it = 0; it < 2; ++it) {
                int e = it * 4096 + tid * 8;
                int dim = e >> 7, kb = (e >> 3) & 15;
                int skb = kb ^ (dim & 7);
                async_copy16(V + (size_t)dim * TT + k0 + skb * 8,
                             Vs + it * 4096 + (tid & ~63) * 8);
            }
            __syncthreads();   // staged

            #pragma unroll
            for (int ch = 0; ch < 2; ++ch) {
                int c64 = k0 + ch * 64;
                if (c64 < kend) {                         // wave-uniform
                    // ---- S^T = K·Q^T - FMAX, 4 subtiles of 16 keys ----
                    f32x4 s[4];
                    #pragma unroll
                    for (int t = 0; t < 4; ++t) {
                        int kt = c64 + 16 * t;
                        if (kt < kend) {                  // wave-uniform
                            int rb = (ch * 64 + 16 * t + c) * 64;
                            bf16x8 kf0 = *(const bf16x8*)(Ks + rb + ((g ^ c7) << 3));
                            bf16x8 kf1 = *(const bf16x8*)(Ks + rb + (((4 + g) ^ c7) << 3));
                            f32x4 a = (f32x4){-FMAX, -FMAX, -FMAX, -FMAX};
                            a = __builtin_amdgcn_mfma_f32_16x16x32_bf16(kf0, aq0, a, 0, 0, 0);
                            a = __builtin_amdgcn_mfma_f32_16x16x32_bf16(kf1, aq1, a, 0, 0, 0);
                            if (kt == q0) {               // diagonal: key<=q ⇔ g*4+r<=c
                                #pragma unroll
                                for (int r = 0; r < 4; ++r)
                                    a[r] = (g * 4 + r <= c) ? a[r] : -1e30f;
                            }
                            s[t] = a;
                        } else
                            s[t] = (f32x4){-1e30f, -1e30f, -1e30f, -1e30f};
                    }
                    // ---- P = exp2(S - FMAX), straight to LDS (no max/sum bookkeeping) ----
                    #pragma unroll
                    for (int t = 0; t < 4; ++t) {
                        f32x4 e;
                        #pragma unroll
                        for (int r = 0; r < 4; ++r) e[r] = __builtin_amdgcn_exp2f(s[t][r]);
                        *(bf16x4*)(Pq + c * 64 + (((2 * t + (g >> 1)) ^ c7) << 3) + ((g & 1) << 2)) =
                            pack4(e[0], e[1], e[2], e[3]);
                    }
                    // ---- O^T += V^T·P^T ; l via ones·P^T (every D row = col-sum) ----
                    #pragma unroll
                    for (int sc = 0; sc < 2; ++sc) {
                        if (c64 + 32 * sc < kend) {       // wave-uniform
                            bf16x8 pf = *(const bf16x8*)(Pq + c * 64 + (((4 * sc + g) ^ c7) << 3));
                            lacc = __builtin_amdgcn_mfma_f32_16x16x32_bf16(ones8, pf, lacc, 0, 0, 0);
                            #pragma unroll
                            for (int d = 0; d < 4; ++d) {
                                int dim = d * 16 + c;
                                bf16x8 vf = *(const bf16x8*)(Vs + dim * 128 +
                                              (((ch * 8 + 4 * sc + g) ^ c7) << 3));
                                o[d] = __builtin_amdgcn_mfma_f32_16x16x32_bf16(vf, pf, o[d], 0, 0, 0);
                            }
                        }
                    }
                }
            }
        }

        float inv = 1.0f / lacc[0];
        #pragma unroll
        for (int d = 0; d < 4; ++d) {
            *(bf16x4*)(y + (size_t)(b * TT + q0 + c) * EMB + h * HD + d * 16 + g * 4) =
                pack4(o[d][0] * inv, o[d][1] * inv, o[d][2] * inv, o[d][3] * inv);
        }
    }
}

// ---------------- GEMM 2: out = y @ W_proj + b_proj ----------------

__global__ __launch_bounds__(256) void gemm_out(
    const hbf* __restrict__ A, const hbf* __restrict__ Bt,
    const float* __restrict__ bias, float* __restrict__ out)
{
    __shared__ __align__(16) hbf As[BM * BK];
    __shared__ __align__(16) hbf Bs[BN * BK];
    int tid = threadIdx.x;
    int wv = tid >> 6, lane = tid & 63;
    int g = lane >> 4, c = lane & 15;
    int wr = wv >> 1, wc = wv & 1;
    int bn = blockIdx.x % (EMB / BN);
    int bm = blockIdx.x / (EMB / BN);
    int m0 = bm * BM, n0 = bn * BN;

    f32x4 acc[4][4];
    #pragma unroll
    for (int i = 0; i < 4; ++i)
        #pragma unroll
        for (int j = 0; j < 4; ++j) acc[i][j] = (f32x4){0.f, 0.f, 0.f, 0.f};

    for (int k0 = 0; k0 < EMB; k0 += BK) {
        const hbf* Ag = A  + (size_t)m0 * EMB + k0;
        const hbf* Bg = Bt + (size_t)n0 * EMB + k0;
        GEMM_STAGE(As, Ag, EMB);
        GEMM_STAGE(Bs, Bg, EMB);
        __syncthreads();
        bf16x8 af[4], bf[4];
        #pragma unroll
        for (int mi = 0; mi < 4; ++mi)
            af[mi] = *(const bf16x8*)(As + (wr * 64 + mi * 16 + c) * BK + g * 8);
        #pragma unroll
        for (int ni = 0; ni < 4; ++ni)
            bf[ni] = *(const bf16x8*)(Bs + (wc * 64 + ni * 16 + c) * BK + g * 8);
        #pragma unroll
        for (int mi = 0; mi < 4; ++mi)
            #pragma unroll
            for (int ni = 0; ni < 4; ++ni)
                acc[mi][ni] = __builtin_amdgcn_mfma_f32_16x16x32_bf16(af[mi], bf[ni], acc[mi][ni], 0, 0, 0);
        __syncthreads();
    }

    #pragma unroll
    for (int mi = 0; mi < 4; ++mi)
        #pragma unroll
        for (int ni = 0; ni < 4; ++ni) {
            int col = n0 + wc * 64 + ni * 16 + c;
            float bv = bias[col];
            #pragma unroll
            for (int r = 0; r < 4; ++r) {
                int row = m0 + wr * 64 + mi * 16 + g * 4 + r;
                out[(size_t)row * EMB + col] = acc[mi][ni][r] + bv;
            }
        }
}

// ---------------- launch ----------------

extern "C" void kernel_launch(void* const* d_in, const int* in_sizes, int n_in,
                              void* d_out, int out_size, void* d_ws, size_t ws_size,
                              hipStream_t stream)
{
    const float* x      = (const float*)d_in[0];
    const float* W_attn = (const float*)d_in[1];
    const float* W_proj = (const float*)d_in[2];
    const float* b_proj = (const float*)d_in[3];
    float* out = (float*)d_out;

    char* ws = (char*)d_ws;
    hbf* xb    = (hbf*)ws; ws += (size_t)MTOT * KD * 2;
    hbf* wab_t = (hbf*)ws; ws += (size_t)N1 * KD * 2;
    hbf* wpb_t = (hbf*)ws; ws += (size_t)EMB * EMB * 2;
    hbf* qh    = (hbf*)ws; ws += (size_t)MTOT * EMB * 2;
    hbf* kh    = (hbf*)ws; ws += (size_t)MTOT * EMB * 2;
    hbf* vt    = (hbf*)ws; ws += (size_t)MTOT * EMB * 2;
    hbf* yb    = (hbf*)ws; ws += (size_t)MTOT * EMB * 2;

    f32_to_bf16_v4<<<(MTOT * KD / 4 + 255) / 256, 256, 0, stream>>>(x, xb, MTOT * KD / 4);
    f32_to_bf16_T<<<(KD / 64) * (N1 / 64), 256, 0, stream>>>(W_attn, wab_t, KD, N1);
    f32_to_bf16_T<<<(KD / 64) * (EMB / 64), 256, 0, stream>>>(W_proj, wpb_t, KD, EMB);

    gemm_qkv<<<(MTOT / BM) * (N1 / BN), 256, 0, stream>>>(xb, wab_t, qh, kh, vt);
    attn<<<BB * NH * 8, 512, 0, stream>>>(qh, kh, vt, yb);
    gemm_out<<<(MTOT / BM) * (EMB / BN), 256, 0, stream>>>(yb, wpb_t, b_proj, out);
}

// Round 2
// 254.205 us; speedup vs baseline: 1.0992x; 1.0025x over previous
//
#include <hip/hip_runtime.h>
#include <hip/hip_bf16.h>

#define NH 16
#define HD 64
#define EMB 1024
#define BB 4
#define TT 2048
#define MTOT (BB*TT)        // 8192 rows
#define N1 (3*NH*HD)        // 3072
#define KD EMB              // 1024

// q scale: (1/sqrt(HD)) * log2(e) — softmax computed in exp2 domain
#define QSCALE 0.18033688011112042f
// fixed softmax "max" in exp2 domain (exact after 1/l normalization)
#define FMAX 14.0f

typedef __bf16 bf16x8 __attribute__((ext_vector_type(8)));
typedef __bf16 bf16x4 __attribute__((ext_vector_type(4)));
typedef float  f32x4  __attribute__((ext_vector_type(4)));
typedef __hip_bfloat16 hbf;

__device__ __forceinline__ void async_copy16(const hbf* g, hbf* l) {
    __builtin_amdgcn_global_load_lds(
        (const __attribute__((address_space(1))) void*)g,
        (__attribute__((address_space(3))) void*)l, 16, 0, 0);
}

__device__ __forceinline__ bf16x4 pack4(float x0, float x1, float x2, float x3) {
    union { bf16x4 v; hbf a[4]; } u;
    u.a[0] = __float2bfloat16(x0);
    u.a[1] = __float2bfloat16(x1);
    u.a[2] = __float2bfloat16(x2);
    u.a[3] = __float2bfloat16(x3);
    return u.v;
}

// ---------------- conversion kernels ----------------

__global__ __launch_bounds__(256) void f32_to_bf16_v4(const float* __restrict__ in,
                                                      hbf* __restrict__ out, int n4) {
    int i = blockIdx.x * blockDim.x + threadIdx.x;
    if (i < n4) {
        float4 v = ((const float4*)in)[i];
        *(bf16x4*)(out + 4 * (size_t)i) = pack4(v.x, v.y, v.z, v.w);
    }
}

// LDS-tiled transposing convert: out[c*R + r] = bf16(in[r*C + c]); R,C % 64 == 0
__global__ __launch_bounds__(256) void f32_to_bf16_T(const float* __restrict__ in,
                                                     hbf* __restrict__ out, int R, int C) {
    __shared__ float T[64][65];
    int bc = blockIdx.x % (C / 64), br = blockIdx.x / (C / 64);
    int r0 = br * 64, c0 = bc * 64;
    int tr = threadIdx.x >> 6, tc = threadIdx.x & 63;
    #pragma unroll
    for (int i = 0; i < 16; ++i)
        T[4 * i + tr][tc] = in[(size_t)(r0 + 4 * i + tr) * C + c0 + tc];
    __syncthreads();
    #pragma unroll
    for (int i = 0; i < 16; ++i)
        out[(size_t)(c0 + 4 * i + tr) * R + r0 + tc] = __float2bfloat16(T[tc][4 * i + tr]);
}

// ---------------- phased GEMM (T3+T4+T2+T5): BM=BN=128, BK=64, 8 waves ----------------
// 2 phases per K-tile (N-frag split). A-frags register-cached across both phases
// → A slot frees after ph0 → lead-2 A prefetch into the live buffer.
// B prefetch lead-1 into the idle buffer. One counted vmcnt(2) per K-tile.
// LDS XOR-swizzle: slot sc of row holds global chunk sc^(row&7); reads apply same XOR.
// MODE 0: qkv scatter epilogue (q*QSCALE, k, v-transposed). MODE 1: f32 + bias.

template<int NBN, int MODE>
__global__ __launch_bounds__(512, 4) void gemm8(
    const hbf* __restrict__ A, const hbf* __restrict__ Bt,
    hbf* __restrict__ qh, hbf* __restrict__ kh, hbf* __restrict__ vt,
    const float* __restrict__ bias, float* __restrict__ out)
{
    constexpr int NKT = KD / 64;                 // 16 K-tiles
    __shared__ __align__(16) hbf As[2 * 128 * 64];   // 32 KB double-buffered A
    __shared__ __align__(16) hbf Bs[2 * 128 * 64];   // 32 KB double-buffered B

    int tid = threadIdx.x;
    int wv = tid >> 6, lane = tid & 63;
    int g = lane >> 4, c = lane & 15;
    int wm = wv >> 2, wn = wv & 3;               // 2M x 4N waves; wave out = 64x32
    int bn = blockIdx.x % NBN, bm = blockIdx.x / NBN;
    int m0 = bm * 128, n0 = bn * 128;

    // staging constants: chunk idx = j*512 + tid; row = j*64 + sr0; slot = tid&7
    // global chunk gc = slot ^ (row&7) = (tid&7) ^ (sr0&7)  (j*64 ≡ 0 mod 8)
    int sr0 = tid >> 3;
    int sgc = (tid & 7) ^ (sr0 & 7);
    const hbf* Asrc0 = A  + (size_t)(m0 + sr0) * KD + sgc * 8;
    const hbf* Asrc1 = A  + (size_t)(m0 + 64 + sr0) * KD + sgc * 8;
    const hbf* Bsrc0 = Bt + (size_t)(n0 + sr0) * KD + sgc * 8;
    const hbf* Bsrc1 = Bt + (size_t)(n0 + 64 + sr0) * KD + sgc * 8;
    int ldst0 = (tid & ~63) * 8;                 // wave-uniform LDS dest, j=0
    int ldst1 = 4096 + (tid & ~63) * 8;          // j=1

#define STAGE_A8(tt, buf) { async_copy16(Asrc0 + (tt) * 64, As + (buf) * 8192 + ldst0); \
                            async_copy16(Asrc1 + (tt) * 64, As + (buf) * 8192 + ldst1); }
#define STAGE_B8(tt, buf) { async_copy16(Bsrc0 + (tt) * 64, Bs + (buf) * 8192 + ldst0); \
                            async_copy16(Bsrc1 + (tt) * 64, Bs + (buf) * 8192 + ldst1); }

    // fragment read offsets (swizzled): row base ≡ 0 mod 8 → r&7 == c&7
    int xr = c & 7;
    int aoff0 = (wm * 64 + c) * 64 + ((g ^ xr) << 3);          // kk=0
    int aoff1 = (wm * 64 + c) * 64 + (((4 + g) ^ xr) << 3);    // kk=1
    int boff0 = (wn * 32 + c) * 64 + ((g ^ xr) << 3);
    int boff1 = (wn * 32 + c) * 64 + (((4 + g) ^ xr) << 3);

    f32x4 acc[4][2];
    #pragma unroll
    for (int i = 0; i < 4; ++i)
        #pragma unroll
        for (int j = 0; j < 2; ++j) acc[i][j] = (f32x4){0.f, 0.f, 0.f, 0.f};

    // prologue: A(0),B(0) → buf0; A(1) → buf1. Allow A(1) in flight.
    STAGE_A8(0, 0);
    STAGE_B8(0, 0);
    STAGE_A8(1, 1);
    asm volatile("s_waitcnt vmcnt(2)" ::: "memory");
    asm volatile("s_barrier" ::: "memory");
    __builtin_amdgcn_sched_barrier(0);

    for (int t = 0; t < NKT; ++t) {
        int cur = t & 1;
        const hbf* Ab = As + cur * 8192;
        const hbf* Bb = Bs + cur * 8192;
        // ---- phase 0: read A-frags (both kk) + B-frag nf=0; stage B(t+1); MFMA nf=0 ----
        bf16x8 af[4][2], bfr[2];
        #pragma unroll
        for (int i = 0; i < 4; ++i) {
            af[i][0] = *(const bf16x8*)(Ab + aoff0 + i * 1024);
            af[i][1] = *(const bf16x8*)(Ab + aoff1 + i * 1024);
        }
        bfr[0] = *(const bf16x8*)(Bb + boff0);
        bfr[1] = *(const bf16x8*)(Bb + boff1);
        if (t + 1 < NKT) STAGE_B8(t + 1, cur ^ 1);
        __builtin_amdgcn_s_setprio(1);
        #pragma unroll
        for (int i = 0; i < 4; ++i) {
            acc[i][0] = __builtin_amdgcn_mfma_f32_16x16x32_bf16(af[i][0], bfr[0], acc[i][0], 0, 0, 0);
            acc[i][0] = __builtin_amdgcn_mfma_f32_16x16x32_bf16(af[i][1], bfr[1], acc[i][0], 0, 0, 0);
        }
        __builtin_amdgcn_s_setprio(0);
        asm volatile("s_barrier" ::: "memory");
        __builtin_amdgcn_sched_barrier(0);
        // ---- phase 1: read B-frag nf=1; stage A(t+2) into freed A slot; MFMA nf=1 ----
        bfr[0] = *(const bf16x8*)(Bb + boff0 + 1024);
        bfr[1] = *(const bf16x8*)(Bb + boff1 + 1024);
        if (t + 2 < NKT) STAGE_A8(t + 2, cur);
        __builtin_amdgcn_s_setprio(1);
        #pragma unroll
        for (int i = 0; i < 4; ++i) {
            acc[i][1] = __builtin_amdgcn_mfma_f32_16x16x32_bf16(af[i][0], bfr[0], acc[i][1], 0, 0, 0);
            acc[i][1] = __builtin_amdgcn_mfma_f32_16x16x32_bf16(af[i][1], bfr[1], acc[i][1], 0, 0, 0);
        }
        __builtin_amdgcn_s_setprio(0);
        // counted wait: allow only A(t+2)'s 2 loads to stay in flight
        if (t + 2 < NKT) { asm volatile("s_waitcnt vmcnt(2)" ::: "memory"); }
        else             { asm volatile("s_waitcnt vmcnt(0)" ::: "memory"); }
        asm volatile("s_barrier" ::: "memory");
        __builtin_amdgcn_sched_barrier(0);
    }

#undef STAGE_A8
#undef STAGE_B8

    if constexpr (MODE == 0) {
        int colbase = n0 + wn * 32;
        int which = colbase >> 10;               // 0:q 1:k 2:v
        int h = (colbase & 1023) >> 6;
        int dbase = colbase & 63;                // 0 or 32 within head
        int b = m0 / TT;
        int trow = (m0 % TT) + wm * 64;
        if (which < 2) {
            float scale = (which == 0) ? QSCALE : 1.0f;
            hbf* dst = ((which == 0) ? qh : kh) + ((size_t)b * NH + h) * TT * HD;
            #pragma unroll
            for (int i = 0; i < 4; ++i)
                #pragma unroll
                for (int nf = 0; nf < 2; ++nf) {
                    int d = dbase + nf * 16 + c;
                    #pragma unroll
                    for (int r = 0; r < 4; ++r) {
                        int trw = trow + i * 16 + g * 4 + r;
                        dst[(size_t)trw * HD + d] = __float2bfloat16(acc[i][nf][r] * scale);
                    }
                }
        } else {
            hbf* dst = vt + ((size_t)b * NH + h) * TT * HD;   // [HD][TT] per head
            #pragma unroll
            for (int i = 0; i < 4; ++i)
                #pragma unroll
                for (int nf = 0; nf < 2; ++nf) {
                    int d = dbase + nf * 16 + c;
                    #pragma unroll
                    for (int r = 0; r < 4; ++r) {
                        int trw = trow + i * 16 + g * 4 + r;
                        dst[(size_t)d * TT + trw] = __float2bfloat16(acc[i][nf][r]);
                    }
                }
        }
    } else {
        #pragma unroll
        for (int i = 0; i < 4; ++i)
            #pragma unroll
            for (int nf = 0; nf < 2; ++nf) {
                int col = n0 + wn * 32 + nf * 16 + c;
                float bv = bias[col];
                #pragma unroll
                for (int r = 0; r < 4; ++r) {
                    int row = m0 + wm * 64 + i * 16 + g * 4 + r;
                    out[(size_t)row * EMB + col] = acc[i][nf][r] + bv;
                }
            }
    }
}

// ---------------- flash attention v5: fixed-max softmax, l via MFMA ----------------

__global__ __launch_bounds__(512, 4) void attn(
    const hbf* __restrict__ qh, const hbf* __restrict__ kh, const hbf* __restrict__ vt,
    hbf* __restrict__ y)
{
    __shared__ __align__(16) hbf Ks[128 * 64];     // 16 KB [key][dim-swz]
    __shared__ __align__(16) hbf Vs[64 * 128];     // 16 KB [dim][key-swz]
    __shared__ __align__(16) hbf Ps[8][16 * 64];   // 16 KB per-wave P^T

    int tid = threadIdx.x;
    int wv = tid >> 6, lane = tid & 63;
    int g = lane >> 4, c = lane & 15;
    int c7 = c & 7;

    int bh = blockIdx.x >> 3;
    int pi = blockIdx.x & 7;
    int b = bh >> 4, h = bh & 15;

    const hbf* Q = qh + (size_t)bh * TT * HD;
    const hbf* K = kh + (size_t)bh * TT * HD;
    const hbf* V = vt + (size_t)bh * TT * HD;   // [HD][TT]
    hbf* Pq = &Ps[wv][0];

    union { bf16x8 v; hbf a[8]; } uo;
    #pragma unroll
    for (int i = 0; i < 8; ++i) uo.a[i] = __float2bfloat16(1.0f);
    const bf16x8 ones8 = uo.v;

    #pragma unroll
    for (int pass = 0; pass < 2; ++pass) {
        int sst = pass ? (15 - pi) : pi;
        int qb = sst * 128;
        int q0 = qb + wv * 16;
        int kend = q0 + 16;
        int kmax = qb + 128;

        bf16x8 aq0 = *(const bf16x8*)(Q + (size_t)(q0 + c) * HD + g * 8);
        bf16x8 aq1 = *(const bf16x8*)(Q + (size_t)(q0 + c) * HD + 32 + g * 8);

        f32x4 lacc = (f32x4){0.f, 0.f, 0.f, 0.f};
        f32x4 o[4];
        #pragma unroll
        for (int d = 0; d < 4; ++d) o[d] = (f32x4){0.f, 0.f, 0.f, 0.f};

        for (int k0 = 0; k0 < kmax; k0 += 128) {
            __syncthreads();
            #pragma unroll
            for (int it = 0; it < 2; ++it) {
                int e = it * 4096 + tid * 8;
                int key = e >> 6, sblk = (e >> 3) & 7;
                int dblk = sblk ^ (key & 7);
                async_copy16(K + (size_t)(k0 + key) * HD + dblk * 8,
                             Ks + it * 4096 + (tid & ~63) * 8);
            }
            #pragma unroll
            for (int it = 0; it < 2; ++it) {
                int e = it * 4096 + tid * 8;
                int dim = e >> 7, kb = (e >> 3) & 15;
                int skb = kb ^ (dim & 7);
                async_copy16(V + (size_t)dim * TT + k0 + skb * 8,
                             Vs + it * 4096 + (tid & ~63) * 8);
            }
            __syncthreads();

            #pragma unroll
            for (int ch = 0; ch < 2; ++ch) {
                int c64 = k0 + ch * 64;
                if (c64 < kend) {
                    f32x4 s[4];
                    #pragma unroll
                    for (int t = 0; t < 4; ++t) {
                        int kt = c64 + 16 * t;
                        if (kt < kend) {
                            int rb = (ch * 64 + 16 * t + c) * 64;
                            bf16x8 kf0 = *(const bf16x8*)(Ks + rb + ((g ^ c7) << 3));
                            bf16x8 kf1 = *(const bf16x8*)(Ks + rb + (((4 + g) ^ c7) << 3));
                            f32x4 a = (f32x4){-FMAX, -FMAX, -FMAX, -FMAX};
                            a = __builtin_amdgcn_mfma_f32_16x16x32_bf16(kf0, aq0, a, 0, 0, 0);
                            a = __builtin_amdgcn_mfma_f32_16x16x32_bf16(kf1, aq1, a, 0, 0, 0);
                            if (kt == q0) {
                                #pragma unroll
                                for (int r = 0; r < 4; ++r)
                                    a[r] = (g * 4 + r <= c) ? a[r] : -1e30f;
                            }
                            s[t] = a;
                        } else
                            s[t] = (f32x4){-1e30f, -1e30f, -1e30f, -1e30f};
                    }
                    #pragma unroll
                    for (int t = 0; t < 4; ++t) {
                        f32x4 e;
                        #pragma unroll
                        for (int r = 0; r < 4; ++r) e[r] = __builtin_amdgcn_exp2f(s[t][r]);
                        *(bf16x4*)(Pq + c * 64 + (((2 * t + (g >> 1)) ^ c7) << 3) + ((g & 1) << 2)) =
                            pack4(e[0], e[1], e[2], e[3]);
                    }
                    #pragma unroll
                    for (int sc = 0; sc < 2; ++sc) {
                        if (c64 + 32 * sc < kend) {
                            bf16x8 pf = *(const bf16x8*)(Pq + c * 64 + (((4 * sc + g) ^ c7) << 3));
                            lacc = __builtin_amdgcn_mfma_f32_16x16x32_bf16(ones8, pf, lacc, 0, 0, 0);
                            #pragma unroll
                            for (int d = 0; d < 4; ++d) {
                                int dim = d * 16 + c;
                                bf16x8 vf = *(const bf16x8*)(Vs + dim * 128 +
                                              (((ch * 8 + 4 * sc + g) ^ c7) << 3));
                                o[d] = __builtin_amdgcn_mfma_f32_16x16x32_bf16(vf, pf, o[d], 0, 0, 0);
                            }
                        }
                    }
                }
            }
        }

        float inv = 1.0f / lacc[0];
        #pragma unroll
        for (int d = 0; d < 4; ++d) {
            *(bf16x4*)(y + (size_t)(b * TT + q0 + c) * EMB + h * HD + d * 16 + g * 4) =
                pack4(o[d][0] * inv, o[d][1] * inv, o[d][2] * inv, o[d][3] * inv);
        }
    }
}

// ---------------- launch ----------------

extern "C" void kernel_launch(void* const* d_in, const int* in_sizes, int n_in,
                              void* d_out, int out_size, void* d_ws, size_t ws_size,
                              hipStream_t stream)
{
    const float* x      = (const float*)d_in[0];
    const float* W_attn = (const float*)d_in[1];
    const float* W_proj = (const float*)d_in[2];
    const float* b_proj = (const float*)d_in[3];
    float* out = (float*)d_out;

    char* ws = (char*)d_ws;
    hbf* xb    = (hbf*)ws; ws += (size_t)MTOT * KD * 2;
    hbf* wab_t = (hbf*)ws; ws += (size_t)N1 * KD * 2;
    hbf* wpb_t = (hbf*)ws; ws += (size_t)EMB * EMB * 2;
    hbf* qh    = (hbf*)ws; ws += (size_t)MTOT * EMB * 2;
    hbf* kh    = (hbf*)ws; ws += (size_t)MTOT * EMB * 2;
    hbf* vt    = (hbf*)ws; ws += (size_t)MTOT * EMB * 2;
    hbf* yb    = (hbf*)ws; ws += (size_t)MTOT * EMB * 2;

    f32_to_bf16_v4<<<(MTOT * KD / 4 + 255) / 256, 256, 0, stream>>>(x, xb, MTOT * KD / 4);
    f32_to_bf16_T<<<(KD / 64) * (N1 / 64), 256, 0, stream>>>(W_attn, wab_t, KD, N1);
    f32_to_bf16_T<<<(KD / 64) * (EMB / 64), 256, 0, stream>>>(W_proj, wpb_t, KD, EMB);

    gemm8<N1 / 128, 0><<<(MTOT / 128) * (N1 / 128), 512, 0, stream>>>(
        xb, wab_t, qh, kh, vt, nullptr, nullptr);
    attn<<<BB * NH * 8, 512, 0, stream>>>(qh, kh, vt, yb);
    gemm8<EMB / 128, 1><<<(MTOT / 128) * (EMB / 128), 512, 0, stream>>>(
        yb, wpb_t, nullptr, nullptr, nullptr, b_proj, out);
}